// Round 10
// baseline (317.235 us; speedup 1.0000x reference)
//
#include <hip/hip_runtime.h>
#include <hip/hip_bf16.h>
#include <hip/hip_fp16.h>

// GQNN: 2-layer GraphSAGE (mean aggr) + fc head. N=100k, E=3.2M, d=64/65.
// R10: packed-fp16 accumulation in aggr. R9 evidence: VALUBusy 58% at 63us
// => aggr is VALU-issue-bound; per-edge cvt+add chain is >half the VALU.
// __hadd2 (v_pk_add_f16) accumulators kill the cvts and halve the adds;
// gather addresses as 32-bit byte offsets (one v_lshl_add_u32, saddr load).
// fp32 conversion only in the epilogue. Precision: fp16 running-sum RMS err
// ~6e-3 on sum -> ~2e-4 on mean -> ~1e-4 at output (threshold 8.28e-3).
// Two-node-per-wave shape (R9), build (R2), MFMA gemms (R7) unchanged.

#define WAVES_PER_BLOCK 16
#define LAYER_BLOCK (WAVES_PER_BLOCK * 64)
#define LAYER_GRID 512

#define BSH 7                    // bucket shift: 128 nodes per bucket
#define NBKT 782                 // ceil(100000 / 128)
#define NBLK 256                 // binning blocks

typedef _Float16 half8 __attribute__((ext_vector_type(8)));
typedef float floatx4 __attribute__((ext_vector_type(4)));

// ---------------- CSR build (unchanged from R2) ----------------

__global__ __launch_bounds__(256) void k_hist(const int* __restrict__ dst,
                                              int* __restrict__ histT, int E) {
    __shared__ int h[NBKT];
    for (int i = threadIdx.x; i < NBKT; i += 256) h[i] = 0;
    __syncthreads();
    int per = (E + NBLK - 1) / NBLK;
    int lo = blockIdx.x * per;
    int hi = lo + per; if (hi > E) hi = E;
    for (int e = lo + threadIdx.x; e < hi; e += 256)
        atomicAdd(&h[dst[e] >> BSH], 1);
    __syncthreads();
    for (int k = threadIdx.x; k < NBKT; k += 256)
        histT[k * NBLK + blockIdx.x] = h[k];
}

__global__ __launch_bounds__(NBLK) void k_scanblk(int* __restrict__ histT,
                                                  int* __restrict__ btot) {
    __shared__ int s[NBLK];
    int k = blockIdx.x, t = threadIdx.x;
    int v = histT[k * NBLK + t];
    s[t] = v;
    __syncthreads();
    for (int off = 1; off < NBLK; off <<= 1) {
        int u = (t >= off) ? s[t - off] : 0;
        __syncthreads();
        s[t] += u;
        __syncthreads();
    }
    histT[k * NBLK + t] = s[t] - v;
    if (t == NBLK - 1) btot[k] = s[t];
}

__global__ __launch_bounds__(1024) void k_scanbkt(const int* __restrict__ btot,
                                                  int* __restrict__ bstart) {
    __shared__ int s[1024];
    int t = threadIdx.x;
    int v = (t < NBKT) ? btot[t] : 0;
    s[t] = v;
    __syncthreads();
    for (int off = 1; off < 1024; off <<= 1) {
        int u = (t >= off) ? s[t - off] : 0;
        __syncthreads();
        s[t] += u;
        __syncthreads();
    }
    if (t < NBKT) bstart[t] = s[t] - v;
    if (t == NBKT - 1) bstart[NBKT] = s[t];
}

__global__ __launch_bounds__(256) void k_scatter(const int* __restrict__ src,
                                                 const int* __restrict__ dst,
                                                 const int* __restrict__ histT,
                                                 const int* __restrict__ bstart,
                                                 int* __restrict__ binned, int E) {
    __shared__ int cur[NBKT];
    int b = blockIdx.x;
    for (int k = threadIdx.x; k < NBKT; k += 256)
        cur[k] = bstart[k] + histT[k * NBLK + b];
    __syncthreads();
    int per = (E + NBLK - 1) / NBLK;
    int lo = b * per;
    int hi = lo + per; if (hi > E) hi = E;
    for (int e = lo + threadIdx.x; e < hi; e += 256) {
        int d = dst[e], s = src[e];
        int pos = atomicAdd(&cur[d >> BSH], 1);
        binned[pos] = (s << BSH) | (d & ((1 << BSH) - 1));
    }
}

__global__ __launch_bounds__(256) void k_bucket(const int* __restrict__ binned,
                                                const int* __restrict__ bstart,
                                                int* __restrict__ rowptr,
                                                int* __restrict__ deg,
                                                int* __restrict__ colidx, int N) {
    __shared__ int cnt[128], sc[128], cur[128];
    int k = blockIdx.x, t = threadIdx.x;
    int lo = bstart[k], hi = bstart[k + 1];
    if (t < 128) cnt[t] = 0;
    __syncthreads();
    for (int e = lo + t; e < hi; e += 256)
        atomicAdd(&cnt[binned[e] & 127], 1);
    __syncthreads();
    if (t < 128) sc[t] = cnt[t];
    __syncthreads();
    for (int off = 1; off < 128; off <<= 1) {
        int u = 0;
        if (t < 128 && t >= off) u = sc[t - off];
        __syncthreads();
        if (t < 128) sc[t] += u;
        __syncthreads();
    }
    if (t < 128) {
        int abs0 = lo + (sc[t] - cnt[t]);
        cur[t] = abs0;
        int gnode = (k << BSH) + t;
        if (gnode < N) { rowptr[gnode] = abs0; deg[gnode] = cnt[t]; }
    }
    __syncthreads();
    for (int e = lo + t; e < hi; e += 256) {
        int p = binned[e];
        int pos = atomicAdd(&cur[p & 127], 1);
        colidx[pos] = p >> BSH;
    }
}

// ---------------- fused prep: x->fp16  +  W->B-fragment swizzle ----------------
__global__ __launch_bounds__(256) void k_prepall(
    const float* __restrict__ x, __half* __restrict__ xh, int n2,
    const float* __restrict__ W1l, const float* __restrict__ W1r,
    const float* __restrict__ W2l, const float* __restrict__ W2r,
    __half* __restrict__ wbuf1, __half* __restrict__ wbuf2) {
    if (blockIdx.x < 9) {
        int idx = blockIdx.x * 256 + threadIdx.x;
        if (idx < 1280) {
            int lane = idx & 63;
            int nt = (idx >> 6) & 3;
            int kstep = idx >> 8;
            int col = nt * 16 + (lane & 15);
            int kbase = kstep * 32 + (lane >> 4) * 8;
#pragma unroll
            for (int j = 0; j < 8; ++j) {
                int k = kbase + j;
                float v;
                if (k < 64)        v = W1l[k * 64 + col];
                else if (k < 128)  v = W1r[(k - 64) * 64 + col];
                else if (k == 128) v = W1l[64 * 64 + col];
                else if (k == 129) v = W1r[64 * 64 + col];
                else v = 0.f;
                wbuf1[(size_t)idx * 8 + j] = __float2half(v);
            }
        } else if (idx < 1280 + 1024) {
            int i2 = idx - 1280;
            int lane = i2 & 63;
            int nt = (i2 >> 6) & 3;
            int kstep = i2 >> 8;
            int col = nt * 16 + (lane & 15);
            int kbase = kstep * 32 + (lane >> 4) * 8;
#pragma unroll
            for (int j = 0; j < 8; ++j) {
                int k = kbase + j;
                float v = (k < 64) ? W2l[k * 64 + col] : W2r[(k - 64) * 64 + col];
                wbuf2[(size_t)i2 * 8 + j] = __float2half(v);
            }
        }
    } else {
        int i = (blockIdx.x - 9) * 256 + threadIdx.x;
        if (i < n2) {
            float2 v = ((const float2*)x)[i];
            ((__half2*)xh)[i] = __floats2half2_rn(v.x, v.y);
        }
    }
}

// ---------------- Aggregation (R10: pk_f16 accumulation) ----------------
// half = lane>>5 selects node (A: 0-31, B: 32-63); c = lane&31 covers cols
// {2c,2c+1}. One bpermute + one v_lshl_add_u32 + one saddr load + one
// v_pk_add_f16 per 2 edges.

__device__ __forceinline__ __half2 gload(const char* base, unsigned off) {
    return *(const __half2*)(base + off);
}

// zm1[node][64] = mean_x (fp16); mt1[node] = mean_tau (fp16)
__global__ __launch_bounds__(LAYER_BLOCK) void k_aggr1(
    const __half* __restrict__ xh, const float* __restrict__ tau,
    const int* __restrict__ rowptr, const int* __restrict__ deg,
    const int* __restrict__ colidx,
    __half* __restrict__ zm1, __half* __restrict__ mt1, int N) {
    int lane = threadIdx.x & 63;
    int half = lane >> 5;
    int c = lane & 31;
    unsigned cb = (unsigned)(c << 2);       // byte offset of this lane's half2
    const char* xb = (const char*)xh;
    int wave = blockIdx.x * WAVES_PER_BLOCK + (threadIdx.x >> 6);
    int nwaves = gridDim.x * WAVES_PER_BLOCK;
    int npairs = N >> 1;   // N even

    for (int pair = wave; pair < npairs; pair += nwaves) {
        int node = pair * 2 + half;
        int start = rowptr[node];
        int d = deg[node];
        __half2 A0 = {(_Float16)0, (_Float16)0}, A1 = A0, A2 = A0, A3 = A0;
        float sumtau = 0.f;
        for (int base = 0; base < d || base < __shfl_xor(d, 32, 64); base += 32) {
            int n = d - base;
            n = (n < 0) ? 0 : (n > 32 ? 32 : n);
            int nmax = max(n, __shfl_xor(n, 32, 64));   // wave-uniform bound
            int sidx = 0;
            if (c < n) {
                sidx = colidx[start + base + c];
                sumtau += tau[sidx];
            }
            int j = 0;
            for (; j + 4 <= nmax; j += 4) {
                int i0 = __builtin_amdgcn_ds_bpermute((half * 32 + j + 0) << 2, sidx);
                int i1 = __builtin_amdgcn_ds_bpermute((half * 32 + j + 1) << 2, sidx);
                int i2 = __builtin_amdgcn_ds_bpermute((half * 32 + j + 2) << 2, sidx);
                int i3 = __builtin_amdgcn_ds_bpermute((half * 32 + j + 3) << 2, sidx);
                __half2 v0 = gload(xb, ((unsigned)i0 << 7) + cb);
                __half2 v1 = gload(xb, ((unsigned)i1 << 7) + cb);
                __half2 v2 = gload(xb, ((unsigned)i2 << 7) + cb);
                __half2 v3 = gload(xb, ((unsigned)i3 << 7) + cb);
                if (j + 0 < n) A0 = __hadd2(A0, v0);
                if (j + 1 < n) A1 = __hadd2(A1, v1);
                if (j + 2 < n) A2 = __hadd2(A2, v2);
                if (j + 3 < n) A3 = __hadd2(A3, v3);
            }
            for (; j < nmax; ++j) {
                int i0 = __builtin_amdgcn_ds_bpermute((half * 32 + j) << 2, sidx);
                __half2 v0 = gload(xb, ((unsigned)i0 << 7) + cb);
                if (j < n) A0 = __hadd2(A0, v0);
            }
        }
        float2 f0 = __half22float2(A0), f1 = __half22float2(A1);
        float2 f2 = __half22float2(A2), f3 = __half22float2(A3);
        float2 A;
        A.x = (f0.x + f1.x) + (f2.x + f3.x);
        A.y = (f0.y + f1.y) + (f2.y + f3.y);
#pragma unroll
        for (int off = 16; off > 0; off >>= 1) sumtau += __shfl_xor(sumtau, off, 64);

        float inv = 1.f / fmaxf((float)d, 1.f);
        ((__half2*)(zm1 + (size_t)node * 64))[c] = __floats2half2_rn(A.x * inv, A.y * inv);
        if (c == 0) mt1[node] = __float2half(sumtau * inv);
    }
}

// zm2[node][64] = mean_h1 (fp16)
__global__ __launch_bounds__(LAYER_BLOCK) void k_aggr2(
    const __half* __restrict__ h1,
    const int* __restrict__ rowptr, const int* __restrict__ deg,
    const int* __restrict__ colidx, __half* __restrict__ zm2, int N) {
    int lane = threadIdx.x & 63;
    int half = lane >> 5;
    int c = lane & 31;
    unsigned cb = (unsigned)(c << 2);
    const char* hb = (const char*)h1;
    int wave = blockIdx.x * WAVES_PER_BLOCK + (threadIdx.x >> 6);
    int nwaves = gridDim.x * WAVES_PER_BLOCK;
    int npairs = N >> 1;

    for (int pair = wave; pair < npairs; pair += nwaves) {
        int node = pair * 2 + half;
        int start = rowptr[node];
        int d = deg[node];
        __half2 A0 = {(_Float16)0, (_Float16)0}, A1 = A0, A2 = A0, A3 = A0;
        for (int base = 0; base < d || base < __shfl_xor(d, 32, 64); base += 32) {
            int n = d - base;
            n = (n < 0) ? 0 : (n > 32 ? 32 : n);
            int nmax = max(n, __shfl_xor(n, 32, 64));
            int sidx = 0;
            if (c < n) sidx = colidx[start + base + c];
            int j = 0;
            for (; j + 4 <= nmax; j += 4) {
                int i0 = __builtin_amdgcn_ds_bpermute((half * 32 + j + 0) << 2, sidx);
                int i1 = __builtin_amdgcn_ds_bpermute((half * 32 + j + 1) << 2, sidx);
                int i2 = __builtin_amdgcn_ds_bpermute((half * 32 + j + 2) << 2, sidx);
                int i3 = __builtin_amdgcn_ds_bpermute((half * 32 + j + 3) << 2, sidx);
                __half2 v0 = gload(hb, ((unsigned)i0 << 7) + cb);
                __half2 v1 = gload(hb, ((unsigned)i1 << 7) + cb);
                __half2 v2 = gload(hb, ((unsigned)i2 << 7) + cb);
                __half2 v3 = gload(hb, ((unsigned)i3 << 7) + cb);
                if (j + 0 < n) A0 = __hadd2(A0, v0);
                if (j + 1 < n) A1 = __hadd2(A1, v1);
                if (j + 2 < n) A2 = __hadd2(A2, v2);
                if (j + 3 < n) A3 = __hadd2(A3, v3);
            }
            for (; j < nmax; ++j) {
                int i0 = __builtin_amdgcn_ds_bpermute((half * 32 + j) << 2, sidx);
                __half2 v0 = gload(hb, ((unsigned)i0 << 7) + cb);
                if (j < n) A0 = __hadd2(A0, v0);
            }
        }
        float2 f0 = __half22float2(A0), f1 = __half22float2(A1);
        float2 f2 = __half22float2(A2), f3 = __half22float2(A3);
        float2 A;
        A.x = (f0.x + f1.x) + (f2.x + f3.x);
        A.y = (f0.y + f1.y) + (f2.y + f3.y);
        float inv = 1.f / fmaxf((float)d, 1.f);
        ((__half2*)(zm2 + (size_t)node * 64))[c] = __floats2half2_rn(A.x * inv, A.y * inv);
    }
}

// ---------------- MFMA GEMM kernels (unchanged from R7) ----------------

__global__ __launch_bounds__(256) void k_gemm1(
    const __half* __restrict__ zm1, const __half* __restrict__ mt1,
    const __half* __restrict__ xh, const float* __restrict__ tau,
    const __half* __restrict__ wbuf1, const float* __restrict__ b1l,
    __half* __restrict__ h1, int ntiles) {
    int tile = blockIdx.x * 4 + (threadIdx.x >> 6);
    if (tile >= ntiles) return;
    int lane = threadIdx.x & 63;
    int sub = lane & 15;
    int quad = lane >> 4;
    int row = tile * 16 + sub;

    floatx4 acc0 = {0.f, 0.f, 0.f, 0.f};
    floatx4 acc1 = {0.f, 0.f, 0.f, 0.f};
    floatx4 acc2 = {0.f, 0.f, 0.f, 0.f};
    floatx4 acc3 = {0.f, 0.f, 0.f, 0.f};

    const _Float16* zrow = (const _Float16*)zm1 + (size_t)row * 64 + quad * 8;
    const _Float16* xrow = (const _Float16*)xh + (size_t)row * 64 + quad * 8;
    const _Float16* wb = (const _Float16*)wbuf1 + (size_t)lane * 8;

    half8 amat[5];
    amat[0] = *(const half8*)(zrow);
    amat[1] = *(const half8*)(zrow + 32);
    amat[2] = *(const half8*)(xrow);
    amat[3] = *(const half8*)(xrow + 32);
    half8 a4 = {0, 0, 0, 0, 0, 0, 0, 0};
    if (quad == 0) {
        a4[0] = ((const _Float16*)mt1)[row];
        a4[1] = (_Float16)tau[row];
    }
    amat[4] = a4;

#pragma unroll
    for (int ks = 0; ks < 5; ++ks) {
        half8 a = amat[ks];
        half8 b0 = *(const half8*)(wb + (size_t)(ks * 4 + 0) * 512);
        half8 b1 = *(const half8*)(wb + (size_t)(ks * 4 + 1) * 512);
        half8 b2 = *(const half8*)(wb + (size_t)(ks * 4 + 2) * 512);
        half8 b3 = *(const half8*)(wb + (size_t)(ks * 4 + 3) * 512);
        acc0 = __builtin_amdgcn_mfma_f32_16x16x32_f16(a, b0, acc0, 0, 0, 0);
        acc1 = __builtin_amdgcn_mfma_f32_16x16x32_f16(a, b1, acc1, 0, 0, 0);
        acc2 = __builtin_amdgcn_mfma_f32_16x16x32_f16(a, b2, acc2, 0, 0, 0);
        acc3 = __builtin_amdgcn_mfma_f32_16x16x32_f16(a, b3, acc3, 0, 0, 0);
    }
    float bv0 = b1l[sub], bv1 = b1l[16 + sub], bv2 = b1l[32 + sub], bv3 = b1l[48 + sub];
#pragma unroll
    for (int reg = 0; reg < 4; ++reg) {
        int r = quad * 4 + reg;
        __half* orow = h1 + (size_t)(tile * 16 + r) * 64;
        orow[sub]      = __float2half(fmaxf(acc0[reg] + bv0, 0.f));
        orow[16 + sub] = __float2half(fmaxf(acc1[reg] + bv1, 0.f));
        orow[32 + sub] = __float2half(fmaxf(acc2[reg] + bv2, 0.f));
        orow[48 + sub] = __float2half(fmaxf(acc3[reg] + bv3, 0.f));
    }
}

__global__ __launch_bounds__(256) void k_gemm2(
    const __half* __restrict__ zm2, const __half* __restrict__ h1,
    const __half* __restrict__ wbuf2, const float* __restrict__ b2l,
    const float* __restrict__ Wfc, const float* __restrict__ bfc,
    float* __restrict__ out, int ntiles) {
    int tile = blockIdx.x * 4 + (threadIdx.x >> 6);
    if (tile >= ntiles) return;
    int lane = threadIdx.x & 63;
    int sub = lane & 15;
    int quad = lane >> 4;
    int row = tile * 16 + sub;

    floatx4 acc0 = {0.f, 0.f, 0.f, 0.f};
    floatx4 acc1 = {0.f, 0.f, 0.f, 0.f};
    floatx4 acc2 = {0.f, 0.f, 0.f, 0.f};
    floatx4 acc3 = {0.f, 0.f, 0.f, 0.f};

    const _Float16* zrow = (const _Float16*)zm2 + (size_t)row * 64 + quad * 8;
    const _Float16* hrow = (const _Float16*)h1 + (size_t)row * 64 + quad * 8;
    const _Float16* wb = (const _Float16*)wbuf2 + (size_t)lane * 8;

    half8 amat[4];
    amat[0] = *(const half8*)(zrow);
    amat[1] = *(const half8*)(zrow + 32);
    amat[2] = *(const half8*)(hrow);
    amat[3] = *(const half8*)(hrow + 32);

#pragma unroll
    for (int ks = 0; ks < 4; ++ks) {
        half8 a = amat[ks];
        half8 b0 = *(const half8*)(wb + (size_t)(ks * 4 + 0) * 512);
        half8 b1 = *(const half8*)(wb + (size_t)(ks * 4 + 1) * 512);
        half8 b2 = *(const half8*)(wb + (size_t)(ks * 4 + 2) * 512);
        half8 b3 = *(const half8*)(wb + (size_t)(ks * 4 + 3) * 512);
        acc0 = __builtin_amdgcn_mfma_f32_16x16x32_f16(a, b0, acc0, 0, 0, 0);
        acc1 = __builtin_amdgcn_mfma_f32_16x16x32_f16(a, b1, acc1, 0, 0, 0);
        acc2 = __builtin_amdgcn_mfma_f32_16x16x32_f16(a, b2, acc2, 0, 0, 0);
        acc3 = __builtin_amdgcn_mfma_f32_16x16x32_f16(a, b3, acc3, 0, 0, 0);
    }
    float bb0 = b2l[sub], bb1 = b2l[16 + sub], bb2 = b2l[32 + sub], bb3 = b2l[48 + sub];
    float wv0 = Wfc[sub], wv1 = Wfc[16 + sub], wv2 = Wfc[32 + sub], wv3 = Wfc[48 + sub];
    float p[4];
#pragma unroll
    for (int reg = 0; reg < 4; ++reg) {
        p[reg] = fmaxf(acc0[reg] + bb0, 0.f) * wv0
               + fmaxf(acc1[reg] + bb1, 0.f) * wv1
               + fmaxf(acc2[reg] + bb2, 0.f) * wv2
               + fmaxf(acc3[reg] + bb3, 0.f) * wv3;
    }
#pragma unroll
    for (int m = 1; m <= 8; m <<= 1) {
#pragma unroll
        for (int reg = 0; reg < 4; ++reg) p[reg] += __shfl_xor(p[reg], m, 64);
    }
    if (sub == 0) {
        float b0 = bfc[0];
#pragma unroll
        for (int reg = 0; reg < 4; ++reg)
            out[tile * 16 + quad * 4 + reg] = p[reg] + b0;
    }
}

extern "C" void kernel_launch(void* const* d_in, const int* in_sizes, int n_in,
                              void* d_out, int out_size, void* d_ws, size_t ws_size,
                              hipStream_t stream) {
    const float* x   = (const float*)d_in[0];
    const int*   ei  = (const int*)d_in[1];
    const float* tau = (const float*)d_in[2];
    const float* W1l = (const float*)d_in[3];
    const float* b1l = (const float*)d_in[4];
    const float* W1r = (const float*)d_in[5];
    const float* W2l = (const float*)d_in[6];
    const float* b2l = (const float*)d_in[7];
    const float* W2r = (const float*)d_in[8];
    const float* Wfc = (const float*)d_in[9];
    const float* bfc = (const float*)d_in[10];
    float* out = (float*)d_out;

    const int N = in_sizes[0] / 64;   // 100000
    const int E = in_sizes[1] / 2;    // 3200000
    const int* src = ei;
    const int* dst = ei + E;

    char* w = (char*)d_ws;
    auto take = [&](size_t b) { char* p = w; w += (b + 255) & ~(size_t)255; return p; };
    int*    histT  = (int*)take((size_t)NBKT * NBLK * 4);
    int*    btot   = (int*)take((size_t)NBKT * 4);
    int*    bstart = (int*)take((size_t)(NBKT + 1) * 4);
    int*    binned = (int*)take((size_t)E * 4);
    int*    rowptr = (int*)take((size_t)N * 4);
    int*    deg    = (int*)take((size_t)N * 4);
    int*    colidx = (int*)take((size_t)E * 4);
    __half* xh     = (__half*)take((size_t)N * 64 * 2);    // 12.8 MB
    __half* h1     = (__half*)take((size_t)N * 64 * 2);    // 12.8 MB
    __half* zm1    = (__half*)take((size_t)N * 64 * 2);    // 12.8 MB
    __half* mt1    = (__half*)take((size_t)N * 2);
    __half* zm2    = (__half*)take((size_t)N * 64 * 2);    // 12.8 MB
    __half* wbuf1  = (__half*)take(1280 * 8 * 2);          // 20 KB
    __half* wbuf2  = (__half*)take(1024 * 8 * 2);          // 16 KB

    int n2 = N * 32;                  // half2 elements for prep
    int pblocks = 9 + (n2 + 255) / 256;
    int ntiles = N / 16;              // 6250 (exact)
    int gblocks = (ntiles + 3) / 4;   // 1563

    k_hist   <<<NBLK, 256, 0, stream>>>(dst, histT, E);
    k_scanblk<<<NBKT, NBLK, 0, stream>>>(histT, btot);
    k_scanbkt<<<1, 1024, 0, stream>>>(btot, bstart);
    k_scatter<<<NBLK, 256, 0, stream>>>(src, dst, histT, bstart, binned, E);
    k_bucket <<<NBKT, 256, 0, stream>>>(binned, bstart, rowptr, deg, colidx, N);
    k_prepall<<<pblocks, 256, 0, stream>>>(x, xh, n2, W1l, W1r, W2l, W2r, wbuf1, wbuf2);
    k_aggr1  <<<LAYER_GRID, LAYER_BLOCK, 0, stream>>>(xh, tau, rowptr, deg, colidx, zm1, mt1, N);
    k_gemm1  <<<gblocks, 256, 0, stream>>>(zm1, mt1, xh, tau, wbuf1, b1l, h1, ntiles);
    k_aggr2  <<<LAYER_GRID, LAYER_BLOCK, 0, stream>>>(h1, rowptr, deg, colidx, zm2, N);
    k_gemm2  <<<gblocks, 256, 0, stream>>>(zm2, h1, wbuf2, b2l, Wfc, bfc, out, ntiles);
}

// Round 11
// 307.922 us; speedup vs baseline: 1.0302x; 1.0302x over previous
//
#include <hip/hip_runtime.h>
#include <hip/hip_bf16.h>
#include <hip/hip_fp16.h>

// GQNN: 2-layer GraphSAGE (mean aggr) + fc head. N=100k, E=3.2M, d=64/65.
// R11: k_bucket fused into the aggregation kernels. R10 evidence: aggr is
// L2-miss/fill-bound (~160MB @ 2.8TB/s = wall; VALUBusy 58->34% with no time
// change), so instruction tweaks are done; the build (~150us) is the biggest
// block. Each aggr block (one per bucket, 512 thr, all 782 co-resident)
// rebuilds the bucket-local CSR in LDS from `binned` (count/scan/fill,
// ~5% of gather cost) — global colidx/rowptr/deg and the k_bucket kernel
// are eliminated. prep fused into hist launch. Gather loop = R10 (pk_f16).

#define BSH 7                    // bucket shift: 128 nodes per bucket
#define NBKT 782                 // ceil(100000 / 128)
#define NBLK 256                 // binning blocks
#define CAP 6144                 // bucket edge capacity (mean 4096, sigma 64)
#define ABLK 512                 // aggr block threads (8 waves)

typedef _Float16 half8 __attribute__((ext_vector_type(8)));
typedef float floatx4 __attribute__((ext_vector_type(4)));

// ---------------- hist + prep (fused) ----------------
// blocks [0, NBLK): edge histogram; [NBLK, NBLK+9): W swizzle; rest: x->fp16.
__global__ __launch_bounds__(256) void k_histprep(
    const int* __restrict__ dst, int* __restrict__ histT, int E,
    const float* __restrict__ x, __half* __restrict__ xh, int n4,
    const float* __restrict__ W1l, const float* __restrict__ W1r,
    const float* __restrict__ W2l, const float* __restrict__ W2r,
    __half* __restrict__ wbuf1, __half* __restrict__ wbuf2) {
    if (blockIdx.x < NBLK) {
        __shared__ int h[NBKT];
        for (int i = threadIdx.x; i < NBKT; i += 256) h[i] = 0;
        __syncthreads();
        int per = (E + NBLK - 1) / NBLK;
        int lo = blockIdx.x * per;
        int hi = lo + per; if (hi > E) hi = E;
        for (int e = lo + threadIdx.x; e < hi; e += 256)
            atomicAdd(&h[dst[e] >> BSH], 1);
        __syncthreads();
        for (int k = threadIdx.x; k < NBKT; k += 256)
            histT[k * NBLK + blockIdx.x] = h[k];
    } else if (blockIdx.x < NBLK + 9) {
        int idx = (blockIdx.x - NBLK) * 256 + threadIdx.x;
        if (idx < 1280) {
            int lane = idx & 63;
            int nt = (idx >> 6) & 3;
            int kstep = idx >> 8;
            int col = nt * 16 + (lane & 15);
            int kbase = kstep * 32 + (lane >> 4) * 8;
#pragma unroll
            for (int j = 0; j < 8; ++j) {
                int k = kbase + j;
                float v;
                if (k < 64)        v = W1l[k * 64 + col];
                else if (k < 128)  v = W1r[(k - 64) * 64 + col];
                else if (k == 128) v = W1l[64 * 64 + col];
                else if (k == 129) v = W1r[64 * 64 + col];
                else v = 0.f;
                wbuf1[(size_t)idx * 8 + j] = __float2half(v);
            }
        } else if (idx < 1280 + 1024) {
            int i2 = idx - 1280;
            int lane = i2 & 63;
            int nt = (i2 >> 6) & 3;
            int kstep = i2 >> 8;
            int col = nt * 16 + (lane & 15);
            int kbase = kstep * 32 + (lane >> 4) * 8;
#pragma unroll
            for (int j = 0; j < 8; ++j) {
                int k = kbase + j;
                float v = (k < 64) ? W2l[k * 64 + col] : W2r[(k - 64) * 64 + col];
                wbuf2[(size_t)i2 * 8 + j] = __float2half(v);
            }
        }
    } else {
        int i = (blockIdx.x - NBLK - 9) * 256 + threadIdx.x;
        if (i < n4) {
            float4 v = ((const float4*)x)[i];
            ((__half2*)xh)[2 * i]     = __floats2half2_rn(v.x, v.y);
            ((__half2*)xh)[2 * i + 1] = __floats2half2_rn(v.z, v.w);
        }
    }
}

// ---------------- scans (unchanged from R2) ----------------

__global__ __launch_bounds__(NBLK) void k_scanblk(int* __restrict__ histT,
                                                  int* __restrict__ btot) {
    __shared__ int s[NBLK];
    int k = blockIdx.x, t = threadIdx.x;
    int v = histT[k * NBLK + t];
    s[t] = v;
    __syncthreads();
    for (int off = 1; off < NBLK; off <<= 1) {
        int u = (t >= off) ? s[t - off] : 0;
        __syncthreads();
        s[t] += u;
        __syncthreads();
    }
    histT[k * NBLK + t] = s[t] - v;
    if (t == NBLK - 1) btot[k] = s[t];
}

__global__ __launch_bounds__(1024) void k_scanbkt(const int* __restrict__ btot,
                                                  int* __restrict__ bstart) {
    __shared__ int s[1024];
    int t = threadIdx.x;
    int v = (t < NBKT) ? btot[t] : 0;
    s[t] = v;
    __syncthreads();
    for (int off = 1; off < 1024; off <<= 1) {
        int u = (t >= off) ? s[t - off] : 0;
        __syncthreads();
        s[t] += u;
        __syncthreads();
    }
    if (t < NBKT) bstart[t] = s[t] - v;
    if (t == NBKT - 1) bstart[NBKT] = s[t];
}

__global__ __launch_bounds__(256) void k_scatter(const int* __restrict__ src,
                                                 const int* __restrict__ dst,
                                                 const int* __restrict__ histT,
                                                 const int* __restrict__ bstart,
                                                 int* __restrict__ binned, int E) {
    __shared__ int cur[NBKT];
    int b = blockIdx.x;
    for (int k = threadIdx.x; k < NBKT; k += 256)
        cur[k] = bstart[k] + histT[k * NBLK + b];
    __syncthreads();
    int per = (E + NBLK - 1) / NBLK;
    int lo = b * per;
    int hi = lo + per; if (hi > E) hi = E;
    for (int e = lo + threadIdx.x; e < hi; e += 256) {
        int d = dst[e], s = src[e];
        int pos = atomicAdd(&cur[d >> BSH], 1);
        binned[pos] = (s << BSH) | (d & ((1 << BSH) - 1));
    }
}

// ---------------- fused bucket-CSR + aggregation ----------------
// One block per bucket (all 782 co-resident: 4 blk/CU x ~26KB LDS).
// Phase 1: bucket-local CSR in LDS (count/scan/fill from binned).
// Phase 2: R10 gather loop; lanes 0-31 = node A, 32-63 = node B;
//          colidx reads served from LDS.

// zm1[node][64] = mean_x (fp16); mt1[node] = mean_tau (fp16)
__global__ __launch_bounds__(ABLK) void k_aggrb1(
    const int* __restrict__ binned, const int* __restrict__ bstart,
    const __half* __restrict__ xh, const float* __restrict__ tau,
    __half* __restrict__ zm1, __half* __restrict__ mt1, int N) {
    __shared__ int cidx[CAP];
    __shared__ int cnt[128], s[128], cur[128];
    int k = blockIdx.x, t = threadIdx.x;
    int lo = bstart[k], hi = bstart[k + 1];
    if (t < 128) cnt[t] = 0;
    __syncthreads();
    for (int e = lo + t; e < hi; e += ABLK)
        atomicAdd(&cnt[binned[e] & 127], 1);
    __syncthreads();
    if (t < 128) s[t] = cnt[t];
    __syncthreads();
    for (int off = 1; off < 128; off <<= 1) {
        int u = 0;
        if (t < 128 && t >= off) u = s[t - off];
        __syncthreads();
        if (t < 128) s[t] += u;
        __syncthreads();
    }
    if (t < 128) cur[t] = s[t] - cnt[t];
    __syncthreads();
    for (int e = lo + t; e < hi; e += ABLK) {
        int p = binned[e];
        int pos = atomicAdd(&cur[p & 127], 1);
        if (pos < CAP) cidx[pos] = p >> BSH;
    }
    __syncthreads();

    int lane = t & 63;
    int halfid = lane >> 5;
    int c = lane & 31;
    unsigned cb = (unsigned)(c << 2);
    const char* xb = (const char*)xh;

    for (int p = (t >> 6); p < 64; p += (ABLK / 64)) {
        int ld = (p << 1) + halfid;
        int node = (k << BSH) + ld;
        int d = cnt[ld];
        int startL = cur[ld] - d;     // cur == end after fill
        int dother = __shfl_xor(d, 32, 64);
        __half2 A0 = {(_Float16)0, (_Float16)0}, A1 = A0, A2 = A0, A3 = A0;
        float sumtau = 0.f;
        for (int base = 0; base < d || base < dother; base += 32) {
            int n = d - base;
            n = (n < 0) ? 0 : (n > 32 ? 32 : n);
            int nmax = max(n, __shfl_xor(n, 32, 64));
            int sidx = 0;
            if (c < n) {
                int ii = startL + base + c;
                if (ii >= CAP) ii = 0;      // overflow guard (statistically unreachable)
                sidx = cidx[ii];
                sumtau += tau[sidx];
            }
            int j = 0;
            for (; j + 4 <= nmax; j += 4) {
                int i0 = __builtin_amdgcn_ds_bpermute((halfid * 32 + j + 0) << 2, sidx);
                int i1 = __builtin_amdgcn_ds_bpermute((halfid * 32 + j + 1) << 2, sidx);
                int i2 = __builtin_amdgcn_ds_bpermute((halfid * 32 + j + 2) << 2, sidx);
                int i3 = __builtin_amdgcn_ds_bpermute((halfid * 32 + j + 3) << 2, sidx);
                __half2 v0 = *(const __half2*)(xb + (((unsigned)i0 << 7) + cb));
                __half2 v1 = *(const __half2*)(xb + (((unsigned)i1 << 7) + cb));
                __half2 v2 = *(const __half2*)(xb + (((unsigned)i2 << 7) + cb));
                __half2 v3 = *(const __half2*)(xb + (((unsigned)i3 << 7) + cb));
                if (j + 0 < n) A0 = __hadd2(A0, v0);
                if (j + 1 < n) A1 = __hadd2(A1, v1);
                if (j + 2 < n) A2 = __hadd2(A2, v2);
                if (j + 3 < n) A3 = __hadd2(A3, v3);
            }
            for (; j < nmax; ++j) {
                int i0 = __builtin_amdgcn_ds_bpermute((halfid * 32 + j) << 2, sidx);
                __half2 v0 = *(const __half2*)(xb + (((unsigned)i0 << 7) + cb));
                if (j < n) A0 = __hadd2(A0, v0);
            }
        }
        float2 f0 = __half22float2(A0), f1 = __half22float2(A1);
        float2 f2 = __half22float2(A2), f3 = __half22float2(A3);
        float2 A;
        A.x = (f0.x + f1.x) + (f2.x + f3.x);
        A.y = (f0.y + f1.y) + (f2.y + f3.y);
#pragma unroll
        for (int off = 16; off > 0; off >>= 1) sumtau += __shfl_xor(sumtau, off, 64);

        float inv = 1.f / fmaxf((float)d, 1.f);
        if (node < N) {
            ((__half2*)(zm1 + (size_t)node * 64))[c] =
                __floats2half2_rn(A.x * inv, A.y * inv);
            if (c == 0) mt1[node] = __float2half(sumtau * inv);
        }
    }
}

// zm2[node][64] = mean_h1 (fp16)
__global__ __launch_bounds__(ABLK) void k_aggrb2(
    const int* __restrict__ binned, const int* __restrict__ bstart,
    const __half* __restrict__ h1, __half* __restrict__ zm2, int N) {
    __shared__ int cidx[CAP];
    __shared__ int cnt[128], s[128], cur[128];
    int k = blockIdx.x, t = threadIdx.x;
    int lo = bstart[k], hi = bstart[k + 1];
    if (t < 128) cnt[t] = 0;
    __syncthreads();
    for (int e = lo + t; e < hi; e += ABLK)
        atomicAdd(&cnt[binned[e] & 127], 1);
    __syncthreads();
    if (t < 128) s[t] = cnt[t];
    __syncthreads();
    for (int off = 1; off < 128; off <<= 1) {
        int u = 0;
        if (t < 128 && t >= off) u = s[t - off];
        __syncthreads();
        if (t < 128) s[t] += u;
        __syncthreads();
    }
    if (t < 128) cur[t] = s[t] - cnt[t];
    __syncthreads();
    for (int e = lo + t; e < hi; e += ABLK) {
        int p = binned[e];
        int pos = atomicAdd(&cur[p & 127], 1);
        if (pos < CAP) cidx[pos] = p >> BSH;
    }
    __syncthreads();

    int lane = t & 63;
    int halfid = lane >> 5;
    int c = lane & 31;
    unsigned cb = (unsigned)(c << 2);
    const char* hb = (const char*)h1;

    for (int p = (t >> 6); p < 64; p += (ABLK / 64)) {
        int ld = (p << 1) + halfid;
        int node = (k << BSH) + ld;
        int d = cnt[ld];
        int startL = cur[ld] - d;
        int dother = __shfl_xor(d, 32, 64);
        __half2 A0 = {(_Float16)0, (_Float16)0}, A1 = A0, A2 = A0, A3 = A0;
        for (int base = 0; base < d || base < dother; base += 32) {
            int n = d - base;
            n = (n < 0) ? 0 : (n > 32 ? 32 : n);
            int nmax = max(n, __shfl_xor(n, 32, 64));
            int sidx = 0;
            if (c < n) {
                int ii = startL + base + c;
                if (ii >= CAP) ii = 0;
                sidx = cidx[ii];
            }
            int j = 0;
            for (; j + 4 <= nmax; j += 4) {
                int i0 = __builtin_amdgcn_ds_bpermute((halfid * 32 + j + 0) << 2, sidx);
                int i1 = __builtin_amdgcn_ds_bpermute((halfid * 32 + j + 1) << 2, sidx);
                int i2 = __builtin_amdgcn_ds_bpermute((halfid * 32 + j + 2) << 2, sidx);
                int i3 = __builtin_amdgcn_ds_bpermute((halfid * 32 + j + 3) << 2, sidx);
                __half2 v0 = *(const __half2*)(hb + (((unsigned)i0 << 7) + cb));
                __half2 v1 = *(const __half2*)(hb + (((unsigned)i1 << 7) + cb));
                __half2 v2 = *(const __half2*)(hb + (((unsigned)i2 << 7) + cb));
                __half2 v3 = *(const __half2*)(hb + (((unsigned)i3 << 7) + cb));
                if (j + 0 < n) A0 = __hadd2(A0, v0);
                if (j + 1 < n) A1 = __hadd2(A1, v1);
                if (j + 2 < n) A2 = __hadd2(A2, v2);
                if (j + 3 < n) A3 = __hadd2(A3, v3);
            }
            for (; j < nmax; ++j) {
                int i0 = __builtin_amdgcn_ds_bpermute((halfid * 32 + j) << 2, sidx);
                __half2 v0 = *(const __half2*)(hb + (((unsigned)i0 << 7) + cb));
                if (j < n) A0 = __hadd2(A0, v0);
            }
        }
        float2 f0 = __half22float2(A0), f1 = __half22float2(A1);
        float2 f2 = __half22float2(A2), f3 = __half22float2(A3);
        float2 A;
        A.x = (f0.x + f1.x) + (f2.x + f3.x);
        A.y = (f0.y + f1.y) + (f2.y + f3.y);
        float inv = 1.f / fmaxf((float)d, 1.f);
        if (node < N)
            ((__half2*)(zm2 + (size_t)node * 64))[c] =
                __floats2half2_rn(A.x * inv, A.y * inv);
    }
}

// ---------------- MFMA GEMM kernels (unchanged from R7) ----------------

__global__ __launch_bounds__(256) void k_gemm1(
    const __half* __restrict__ zm1, const __half* __restrict__ mt1,
    const __half* __restrict__ xh, const float* __restrict__ tau,
    const __half* __restrict__ wbuf1, const float* __restrict__ b1l,
    __half* __restrict__ h1, int ntiles) {
    int tile = blockIdx.x * 4 + (threadIdx.x >> 6);
    if (tile >= ntiles) return;
    int lane = threadIdx.x & 63;
    int sub = lane & 15;
    int quad = lane >> 4;
    int row = tile * 16 + sub;

    floatx4 acc0 = {0.f, 0.f, 0.f, 0.f};
    floatx4 acc1 = {0.f, 0.f, 0.f, 0.f};
    floatx4 acc2 = {0.f, 0.f, 0.f, 0.f};
    floatx4 acc3 = {0.f, 0.f, 0.f, 0.f};

    const _Float16* zrow = (const _Float16*)zm1 + (size_t)row * 64 + quad * 8;
    const _Float16* xrow = (const _Float16*)xh + (size_t)row * 64 + quad * 8;
    const _Float16* wb = (const _Float16*)wbuf1 + (size_t)lane * 8;

    half8 amat[5];
    amat[0] = *(const half8*)(zrow);
    amat[1] = *(const half8*)(zrow + 32);
    amat[2] = *(const half8*)(xrow);
    amat[3] = *(const half8*)(xrow + 32);
    half8 a4 = {0, 0, 0, 0, 0, 0, 0, 0};
    if (quad == 0) {
        a4[0] = ((const _Float16*)mt1)[row];
        a4[1] = (_Float16)tau[row];
    }
    amat[4] = a4;

#pragma unroll
    for (int ks = 0; ks < 5; ++ks) {
        half8 a = amat[ks];
        half8 b0 = *(const half8*)(wb + (size_t)(ks * 4 + 0) * 512);
        half8 b1 = *(const half8*)(wb + (size_t)(ks * 4 + 1) * 512);
        half8 b2 = *(const half8*)(wb + (size_t)(ks * 4 + 2) * 512);
        half8 b3 = *(const half8*)(wb + (size_t)(ks * 4 + 3) * 512);
        acc0 = __builtin_amdgcn_mfma_f32_16x16x32_f16(a, b0, acc0, 0, 0, 0);
        acc1 = __builtin_amdgcn_mfma_f32_16x16x32_f16(a, b1, acc1, 0, 0, 0);
        acc2 = __builtin_amdgcn_mfma_f32_16x16x32_f16(a, b2, acc2, 0, 0, 0);
        acc3 = __builtin_amdgcn_mfma_f32_16x16x32_f16(a, b3, acc3, 0, 0, 0);
    }
    float bv0 = b1l[sub], bv1 = b1l[16 + sub], bv2 = b1l[32 + sub], bv3 = b1l[48 + sub];
#pragma unroll
    for (int reg = 0; reg < 4; ++reg) {
        int r = quad * 4 + reg;
        __half* orow = h1 + (size_t)(tile * 16 + r) * 64;
        orow[sub]      = __float2half(fmaxf(acc0[reg] + bv0, 0.f));
        orow[16 + sub] = __float2half(fmaxf(acc1[reg] + bv1, 0.f));
        orow[32 + sub] = __float2half(fmaxf(acc2[reg] + bv2, 0.f));
        orow[48 + sub] = __float2half(fmaxf(acc3[reg] + bv3, 0.f));
    }
}

__global__ __launch_bounds__(256) void k_gemm2(
    const __half* __restrict__ zm2, const __half* __restrict__ h1,
    const __half* __restrict__ wbuf2, const float* __restrict__ b2l,
    const float* __restrict__ Wfc, const float* __restrict__ bfc,
    float* __restrict__ out, int ntiles) {
    int tile = blockIdx.x * 4 + (threadIdx.x >> 6);
    if (tile >= ntiles) return;
    int lane = threadIdx.x & 63;
    int sub = lane & 15;
    int quad = lane >> 4;
    int row = tile * 16 + sub;

    floatx4 acc0 = {0.f, 0.f, 0.f, 0.f};
    floatx4 acc1 = {0.f, 0.f, 0.f, 0.f};
    floatx4 acc2 = {0.f, 0.f, 0.f, 0.f};
    floatx4 acc3 = {0.f, 0.f, 0.f, 0.f};

    const _Float16* zrow = (const _Float16*)zm2 + (size_t)row * 64 + quad * 8;
    const _Float16* hrow = (const _Float16*)h1 + (size_t)row * 64 + quad * 8;
    const _Float16* wb = (const _Float16*)wbuf2 + (size_t)lane * 8;

    half8 amat[4];
    amat[0] = *(const half8*)(zrow);
    amat[1] = *(const half8*)(zrow + 32);
    amat[2] = *(const half8*)(hrow);
    amat[3] = *(const half8*)(hrow + 32);

#pragma unroll
    for (int ks = 0; ks < 4; ++ks) {
        half8 a = amat[ks];
        half8 b0 = *(const half8*)(wb + (size_t)(ks * 4 + 0) * 512);
        half8 b1 = *(const half8*)(wb + (size_t)(ks * 4 + 1) * 512);
        half8 b2 = *(const half8*)(wb + (size_t)(ks * 4 + 2) * 512);
        half8 b3 = *(const half8*)(wb + (size_t)(ks * 4 + 3) * 512);
        acc0 = __builtin_amdgcn_mfma_f32_16x16x32_f16(a, b0, acc0, 0, 0, 0);
        acc1 = __builtin_amdgcn_mfma_f32_16x16x32_f16(a, b1, acc1, 0, 0, 0);
        acc2 = __builtin_amdgcn_mfma_f32_16x16x32_f16(a, b2, acc2, 0, 0, 0);
        acc3 = __builtin_amdgcn_mfma_f32_16x16x32_f16(a, b3, acc3, 0, 0, 0);
    }
    float bb0 = b2l[sub], bb1 = b2l[16 + sub], bb2 = b2l[32 + sub], bb3 = b2l[48 + sub];
    float wv0 = Wfc[sub], wv1 = Wfc[16 + sub], wv2 = Wfc[32 + sub], wv3 = Wfc[48 + sub];
    float p[4];
#pragma unroll
    for (int reg = 0; reg < 4; ++reg) {
        p[reg] = fmaxf(acc0[reg] + bb0, 0.f) * wv0
               + fmaxf(acc1[reg] + bb1, 0.f) * wv1
               + fmaxf(acc2[reg] + bb2, 0.f) * wv2
               + fmaxf(acc3[reg] + bb3, 0.f) * wv3;
    }
#pragma unroll
    for (int m = 1; m <= 8; m <<= 1) {
#pragma unroll
        for (int reg = 0; reg < 4; ++reg) p[reg] += __shfl_xor(p[reg], m, 64);
    }
    if (sub == 0) {
        float b0 = bfc[0];
#pragma unroll
        for (int reg = 0; reg < 4; ++reg)
            out[tile * 16 + quad * 4 + reg] = p[reg] + b0;
    }
}

extern "C" void kernel_launch(void* const* d_in, const int* in_sizes, int n_in,
                              void* d_out, int out_size, void* d_ws, size_t ws_size,
                              hipStream_t stream) {
    const float* x   = (const float*)d_in[0];
    const int*   ei  = (const int*)d_in[1];
    const float* tau = (const float*)d_in[2];
    const float* W1l = (const float*)d_in[3];
    const float* b1l = (const float*)d_in[4];
    const float* W1r = (const float*)d_in[5];
    const float* W2l = (const float*)d_in[6];
    const float* b2l = (const float*)d_in[7];
    const float* W2r = (const float*)d_in[8];
    const float* Wfc = (const float*)d_in[9];
    const float* bfc = (const float*)d_in[10];
    float* out = (float*)d_out;

    const int N = in_sizes[0] / 64;   // 100000
    const int E = in_sizes[1] / 2;    // 3200000
    const int* src = ei;
    const int* dst = ei + E;

    char* w = (char*)d_ws;
    auto take = [&](size_t b) { char* p = w; w += (b + 255) & ~(size_t)255; return p; };
    int*    histT  = (int*)take((size_t)NBKT * NBLK * 4);
    int*    btot   = (int*)take((size_t)NBKT * 4);
    int*    bstart = (int*)take((size_t)(NBKT + 1) * 4);
    int*    binned = (int*)take((size_t)E * 4);             // 12.8 MB
    __half* xh     = (__half*)take((size_t)N * 64 * 2);     // 12.8 MB
    __half* h1     = (__half*)take((size_t)N * 64 * 2);     // 12.8 MB
    __half* zm1    = (__half*)take((size_t)N * 64 * 2);     // 12.8 MB
    __half* mt1    = (__half*)take((size_t)N * 2);
    __half* zm2    = (__half*)take((size_t)N * 64 * 2);     // 12.8 MB
    __half* wbuf1  = (__half*)take(1280 * 8 * 2);           // 20 KB
    __half* wbuf2  = (__half*)take(1024 * 8 * 2);           // 16 KB

    int n4 = N * 16;                       // float4 elements of x
    int hpblocks = NBLK + 9 + (n4 + 255) / 256;
    int ntiles = N / 16;                   // 6250 (exact)
    int gblocks = (ntiles + 3) / 4;        // 1563

    k_histprep<<<hpblocks, 256, 0, stream>>>(dst, histT, E, x, xh, n4,
                                             W1l, W1r, W2l, W2r, wbuf1, wbuf2);
    k_scanblk <<<NBKT, NBLK, 0, stream>>>(histT, btot);
    k_scanbkt <<<1, 1024, 0, stream>>>(btot, bstart);
    k_scatter <<<NBLK, 256, 0, stream>>>(src, dst, histT, bstart, binned, E);
    k_aggrb1  <<<NBKT, ABLK, 0, stream>>>(binned, bstart, xh, tau, zm1, mt1, N);
    k_gemm1   <<<gblocks, 256, 0, stream>>>(zm1, mt1, xh, tau, wbuf1, b1l, h1, ntiles);
    k_aggrb2  <<<NBKT, ABLK, 0, stream>>>(binned, bstart, h1, zm2, N);
    k_gemm2   <<<gblocks, 256, 0, stream>>>(zm2, h1, wbuf2, b2l, Wfc, bfc, out, ntiles);
}